// Round 8
// baseline (248.051 us; speedup 1.0000x reference)
//
#include <hip/hip_runtime.h>
#include <hip/hip_bf16.h>

#define SN 2048      // sequence length
#define HD 256       // hidden
#define NHEAD 8
#define DK 32
#define BH 16

typedef __bf16 bf16;
typedef __bf16 bf16x8 __attribute__((ext_vector_type(8)));
typedef __bf16 bf16x4 __attribute__((ext_vector_type(4)));
typedef float f32x4 __attribute__((ext_vector_type(4)));
typedef int i32x4 __attribute__((ext_vector_type(4)));

// ---------------------------------------------------------------------------
// Kernel 1: transpose Wq/Wk/Wv/Wo (fp32 -> bf16, [k][n] -> [n][k]) for the
// MFMA B-fragments. 4 blocks, one per matrix.  [validated R6]
// ---------------------------------------------------------------------------
__global__ void __launch_bounds__(256) prep_wt_kernel(
    const float* __restrict__ Wq, const float* __restrict__ Wk,
    const float* __restrict__ Wv, const float* __restrict__ Wo,
    bf16* __restrict__ wt)
{
    __shared__ bf16 tile[32][HD + 8];
    int bid = blockIdx.x;
    int t = threadIdx.x;
    const float* W = bid == 0 ? Wq : bid == 1 ? Wk : bid == 2 ? Wv : Wo;
    bf16* Wt = wt + bid * HD * HD;
    for (int r0 = 0; r0 < HD; r0 += 32) {
        #pragma unroll
        for (int i = 0; i < 32; i++) tile[i][t] = (bf16)W[(r0 + i) * HD + t];
        __syncthreads();
        #pragma unroll
        for (int i = 0; i < 32; i++) Wt[t * HD + r0 + i] = tile[i][t];
        __syncthreads();
    }
}

// ---------------------------------------------------------------------------
// 2048x256 @ 256x256 GEMM (MFMA 16x16x32 bf16), Wt in [n][k] layout.
// AF32: A operand fp32, converted in-register.   [validated R6]
// MODE 0: out[m][n] row-major; MODE 1: out[n][m] transposed (for V). [R5]
// OUTF32: store fp32 (final output) instead of bf16.
// ---------------------------------------------------------------------------
template<bool AF32, int MODE, bool OUTF32>
__device__ __forceinline__ void gemm_body(
    const void* __restrict__ Ap, const bf16* __restrict__ Wt,
    const float* __restrict__ bias, void* __restrict__ outp, int bid)
{
    int wave = threadIdx.x >> 6, lane = threadIdx.x & 63;
    int g = lane >> 4, qi = lane & 15;
    int mblk = bid & 31, nblk = bid >> 5;
    int m0 = mblk * 64 + wave * 16, n0 = nblk * 32;
    f32x4 acc0 = {0.f, 0.f, 0.f, 0.f}, acc1 = {0.f, 0.f, 0.f, 0.f};
    const bf16* W0 = Wt + (n0 + qi) * HD + 8 * g;
    const bf16* W1 = W0 + 16 * HD;
    #pragma unroll
    for (int ks = 0; ks < 8; ks++) {
        bf16x8 a;
        if constexpr (AF32) {
            const float* Ar = (const float*)Ap + (m0 + qi) * HD + 8 * g + ks * 32;
            f32x4 lo = *(const f32x4*)Ar;
            f32x4 hi = *(const f32x4*)(Ar + 4);
            #pragma unroll
            for (int e = 0; e < 4; e++) { a[e] = (bf16)lo[e]; a[4 + e] = (bf16)hi[e]; }
        } else {
            a = *(const bf16x8*)((const bf16*)Ap + (m0 + qi) * HD + 8 * g + ks * 32);
        }
        bf16x8 b0 = *(const bf16x8*)(W0 + ks * 32);
        bf16x8 b1 = *(const bf16x8*)(W1 + ks * 32);
        acc0 = __builtin_amdgcn_mfma_f32_16x16x32_bf16(a, b0, acc0, 0, 0, 0);
        acc1 = __builtin_amdgcn_mfma_f32_16x16x32_bf16(a, b1, acc1, 0, 0, 0);
    }
    float bv0 = bias[n0 + qi], bv1 = bias[n0 + 16 + qi];
    if constexpr (MODE == 0) {
        if constexpr (OUTF32) {
            float* out = (float*)outp;
            #pragma unroll
            for (int r = 0; r < 4; r++) {
                int m = m0 + 4 * g + r;
                out[m * HD + n0 + qi]      = acc0[r] + bv0;
                out[m * HD + n0 + 16 + qi] = acc1[r] + bv1;
            }
        } else {
            bf16* out = (bf16*)outp;
            #pragma unroll
            for (int r = 0; r < 4; r++) {
                int m = m0 + 4 * g + r;
                out[m * HD + n0 + qi]      = (bf16)(acc0[r] + bv0);
                out[m * HD + n0 + 16 + qi] = (bf16)(acc1[r] + bv1);
            }
        }
    } else {
        bf16* out = (bf16*)outp;
        bf16x4 v0, v1;
        #pragma unroll
        for (int r = 0; r < 4; r++) { v0[r] = (bf16)(acc0[r] + bv0); v1[r] = (bf16)(acc1[r] + bv1); }
        *(bf16x4*)(out + (n0 + qi) * SN + m0 + 4 * g)      = v0;
        *(bf16x4*)(out + (n0 + 16 + qi) * SN + m0 + 4 * g) = v1;
    }
}

__global__ void __launch_bounds__(256) qkv_kernel(
    const float* __restrict__ q, const float* __restrict__ k, const float* __restrict__ v,
    const bf16* __restrict__ wt,
    const float* __restrict__ bq, const float* __restrict__ bk, const float* __restrict__ bv,
    bf16* __restrict__ qh, bf16* __restrict__ kh, bf16* __restrict__ vt)
{
    int w = blockIdx.y;
    if (w == 0)      gemm_body<true, 0, false>(q, wt,               bq, qh, blockIdx.x);
    else if (w == 1) gemm_body<true, 0, false>(k, wt + HD * HD,     bk, kh, blockIdx.x);
    else             gemm_body<true, 1, false>(v, wt + 2 * HD * HD, bv, vt, blockIdx.x);
}

__global__ void __launch_bounds__(256) oproj_kernel(
    const bf16* __restrict__ A, const bf16* __restrict__ wt3,
    const float* __restrict__ bo, float* __restrict__ out)
{
    gemm_body<false, 0, true>(A, wt3, bo, out, blockIdx.x);
}

// ---------------------------------------------------------------------------
// Kernel 3: MFMA flash attention, swapped-QK^T, bias fused on-the-fly from
// the fp32 maps. [validated: R5 output == R6 naive-VALU output]
// bias(q,k) = ad*dist + ac*contact + bl*label + dl  (affine MLP fold, fp32)
// S^T = mfma(K_rows, Q^T): lane (g,qi) reg r holds S^T[key=16s+4g+r][q=qi].
// P re-fragmented via per-wave LDS [q][key], __syncthreads() both sides.
// grid: bid = h*64 + qb -> bid%8 == qb%8: all 8 heads of a q-strip share an
// XCD -> map rows hit L2 7 of 8 times.
// ---------------------------------------------------------------------------
__global__ void __launch_bounds__(128) attn_kernel(
    const bf16* __restrict__ qh, const bf16* __restrict__ kh,
    const bf16* __restrict__ vt,
    const int* __restrict__ label, const float* __restrict__ dist,
    const float* __restrict__ contact,
    const float* __restrict__ Wd1, const float* __restrict__ bd1,
    const float* __restrict__ Wd2, const float* __restrict__ bd2,
    const float* __restrict__ Wc1, const float* __restrict__ bc1,
    const float* __restrict__ Wc2, const float* __restrict__ bc2,
    bf16* __restrict__ aout)
{
    int wave = threadIdx.x >> 6, lane = threadIdx.x & 63;
    int g = lane >> 4, qi = lane & 15;
    int h = blockIdx.x >> 6, qb = blockIdx.x & 63;
    int q0 = qb * 32 + wave * 16;

    float ad = 0.f, bld = 0.f, dd = bd2[0];
    #pragma unroll
    for (int j = 0; j < BH; j++) {
        float w2 = Wd2[j];
        ad  += Wd1[j] * w2;
        bld += Wd1[BH + j] * w2;
        dd  += bd1[j] * w2;
    }
    float ac = 0.f, blc = 0.f, dc = bc2[0];
    #pragma unroll
    for (int j = 0; j < BH; j++) {
        float w2 = Wc2[j];
        ac  += Wc1[j] * w2;
        blc += Wc1[BH + j] * w2;
        dc  += bc1[j] * w2;
    }
    float bl = bld + blc, dl = dd + dc;

    __shared__ bf16 plds[2][16][72];
    bf16 (*P)[72] = plds[wave];

    bf16x8 qf = *(const bf16x8*)(qh + (q0 + qi) * HD + h * DK + 8 * g);
    const bf16* kp  = kh + h * DK + 8 * g;
    const bf16* v0p = vt + (h * DK + qi) * SN + 8 * g;
    const bf16* v1p = v0p + 16 * SN;
    const float* dp = dist    + (q0 + qi) * SN + 4 * g;
    const float* cp = contact + (q0 + qi) * SN + 4 * g;
    const int*   lp = label   + (q0 + qi) * SN + 4 * g;

    const float scale = 0.17677669529663687f;  // 32^-0.5
    float m = -1e30f, lsum = 0.f;
    f32x4 o0 = {0.f, 0.f, 0.f, 0.f}, o1 = {0.f, 0.f, 0.f, 0.f};

    for (int kt = 0; kt < 32; kt++) {
        int key0 = kt * 64;
        bf16x8 kf0 = *(const bf16x8*)(kp + (key0 +  0 + qi) * HD);
        bf16x8 kf1 = *(const bf16x8*)(kp + (key0 + 16 + qi) * HD);
        bf16x8 kf2 = *(const bf16x8*)(kp + (key0 + 32 + qi) * HD);
        bf16x8 kf3 = *(const bf16x8*)(kp + (key0 + 48 + qi) * HD);
        f32x4 dv0 = *(const f32x4*)(dp + key0 +  0), dv1 = *(const f32x4*)(dp + key0 + 16);
        f32x4 dv2 = *(const f32x4*)(dp + key0 + 32), dv3 = *(const f32x4*)(dp + key0 + 48);
        f32x4 cv0 = *(const f32x4*)(cp + key0 +  0), cv1 = *(const f32x4*)(cp + key0 + 16);
        f32x4 cv2 = *(const f32x4*)(cp + key0 + 32), cv3 = *(const f32x4*)(cp + key0 + 48);
        i32x4 lv0 = *(const i32x4*)(lp + key0 +  0), lv1 = *(const i32x4*)(lp + key0 + 16);
        i32x4 lv2 = *(const i32x4*)(lp + key0 + 32), lv3 = *(const i32x4*)(lp + key0 + 48);
        f32x4 zero = {0.f, 0.f, 0.f, 0.f};
        f32x4 s0 = __builtin_amdgcn_mfma_f32_16x16x32_bf16(kf0, qf, zero, 0, 0, 0);
        f32x4 s1 = __builtin_amdgcn_mfma_f32_16x16x32_bf16(kf1, qf, zero, 0, 0, 0);
        f32x4 s2 = __builtin_amdgcn_mfma_f32_16x16x32_bf16(kf2, qf, zero, 0, 0, 0);
        f32x4 s3 = __builtin_amdgcn_mfma_f32_16x16x32_bf16(kf3, qf, zero, 0, 0, 0);
        float x[16];
        #pragma unroll
        for (int r = 0; r < 4; r++) {
            float b0 = ad * dv0[r] + ac * cv0[r] + bl * (float)lv0[r] + dl;
            float b1 = ad * dv1[r] + ac * cv1[r] + bl * (float)lv1[r] + dl;
            float b2 = ad * dv2[r] + ac * cv2[r] + bl * (float)lv2[r] + dl;
            float b3 = ad * dv3[r] + ac * cv3[r] + bl * (float)lv3[r] + dl;
            x[r]      = s0[r] * scale + b0;
            x[4 + r]  = s1[r] * scale + b1;
            x[8 + r]  = s2[r] * scale + b2;
            x[12 + r] = s3[r] * scale + b3;
        }
        float tm = x[0];
        #pragma unroll
        for (int i = 1; i < 16; i++) tm = fmaxf(tm, x[i]);
        tm = fmaxf(tm, __shfl_xor(tm, 16));
        tm = fmaxf(tm, __shfl_xor(tm, 32));
        float mnew = fmaxf(m, tm);
        float f = __expf(m - mnew);
        float ps = 0.f;
        #pragma unroll
        for (int i = 0; i < 16; i++) { x[i] = __expf(x[i] - mnew); ps += x[i]; }
        ps += __shfl_xor(ps, 16);
        ps += __shfl_xor(ps, 32);
        lsum = lsum * f + ps;
        m = mnew;
        #pragma unroll
        for (int r = 0; r < 4; r++) { o0[r] *= f; o1[r] *= f; }
        #pragma unroll
        for (int s = 0; s < 4; s++) {
            bf16x4 pv;
            #pragma unroll
            for (int r = 0; r < 4; r++) pv[r] = (bf16)x[s * 4 + r];
            *(bf16x4*)(&P[qi][16 * s + 4 * g]) = pv;
        }
        __syncthreads();                       // write -> cross-lane read
        bf16x4 pa0 = *(const bf16x4*)(&P[qi][8 * g]);
        bf16x4 pa1 = *(const bf16x4*)(&P[qi][8 * g + 4]);
        bf16x4 pa2 = *(const bf16x4*)(&P[qi][32 + 8 * g]);
        bf16x4 pa3 = *(const bf16x4*)(&P[qi][32 + 8 * g + 4]);
        bf16x8 pb0 = __builtin_shufflevector(pa0, pa1, 0, 1, 2, 3, 4, 5, 6, 7);
        bf16x8 pb1 = __builtin_shufflevector(pa2, pa3, 0, 1, 2, 3, 4, 5, 6, 7);
        bf16x8 va00 = *(const bf16x8*)(v0p + key0);
        bf16x8 va01 = *(const bf16x8*)(v0p + key0 + 32);
        bf16x8 va10 = *(const bf16x8*)(v1p + key0);
        bf16x8 va11 = *(const bf16x8*)(v1p + key0 + 32);
        o0 = __builtin_amdgcn_mfma_f32_16x16x32_bf16(va00, pb0, o0, 0, 0, 0);
        o0 = __builtin_amdgcn_mfma_f32_16x16x32_bf16(va01, pb1, o0, 0, 0, 0);
        o1 = __builtin_amdgcn_mfma_f32_16x16x32_bf16(va10, pb0, o1, 0, 0, 0);
        o1 = __builtin_amdgcn_mfma_f32_16x16x32_bf16(va11, pb1, o1, 0, 0, 0);
        __syncthreads();                       // read -> next-iter write (WAR)
    }
    float inv = 1.f / lsum;
    bf16x4 r0, r1;
    #pragma unroll
    for (int r = 0; r < 4; r++) { r0[r] = (bf16)(o0[r] * inv); r1[r] = (bf16)(o1[r] * inv); }
    *(bf16x4*)(aout + (q0 + qi) * HD + h * DK + 4 * g)      = r0;
    *(bf16x4*)(aout + (q0 + qi) * HD + h * DK + 16 + 4 * g) = r1;
}

// ---------------------------------------------------------------------------
extern "C" void kernel_launch(void* const* d_in, const int* in_sizes, int n_in,
                              void* d_out, int out_size, void* d_ws, size_t ws_size,
                              hipStream_t stream)
{
    // Inputs fp32 (labels int32); OUTPUT fp32 (reference output dtype).
    static const int expect[22] = {
        SN * SN, SN * SN, SN * SN,
        SN * HD, SN * HD, SN * HD,
        HD * HD, HD, HD * HD, HD,
        HD * HD, HD, HD * HD, HD,
        2 * BH, BH, BH, 1,
        2 * BH, BH, BH, 1
    };
    if (n_in != 22) return;
    for (int i = 0; i < 22; i++) if (in_sizes[i] != expect[i]) return;

    const int*   label   = (const int*)  d_in[0];
    const float* dist    = (const float*)d_in[1];
    const float* contact = (const float*)d_in[2];
    const float* q  = (const float*)d_in[3];
    const float* k  = (const float*)d_in[4];
    const float* v  = (const float*)d_in[5];
    const float* Wq = (const float*)d_in[6];  const float* bq = (const float*)d_in[7];
    const float* Wk = (const float*)d_in[8];  const float* bk = (const float*)d_in[9];
    const float* Wv = (const float*)d_in[10]; const float* bv = (const float*)d_in[11];
    const float* Wo = (const float*)d_in[12]; const float* bo = (const float*)d_in[13];
    const float* Wd1 = (const float*)d_in[14]; const float* bd1 = (const float*)d_in[15];
    const float* Wd2 = (const float*)d_in[16]; const float* bd2 = (const float*)d_in[17];
    const float* Wc1 = (const float*)d_in[18]; const float* bc1 = (const float*)d_in[19];
    const float* Wc2 = (const float*)d_in[20]; const float* bc2 = (const float*)d_in[21];

    // ws: 4.5 MB
    char* ws = (char*)d_ws;
    bf16* qh   = (bf16*)(ws);                 // 1 MB projected Q [N][256]
    bf16* kh   = (bf16*)(ws + (1u << 20));    // 1 MB projected K [N][256]
    bf16* vt   = (bf16*)(ws + (2u << 20));    // 1 MB projected V transposed [256][N]
    bf16* aout = (bf16*)(ws + (3u << 20));    // 1 MB attention output [N][256]
    bf16* wt   = (bf16*)(ws + (4u << 20));    // 512 KB transposed weights x4

    prep_wt_kernel<<<dim3(4), 256, 0, stream>>>(Wq, Wk, Wv, Wo, wt);

    qkv_kernel<<<dim3(256, 3), 256, 0, stream>>>(q, k, v, wt, bq, bk, bv, qh, kh, vt);

    attn_kernel<<<dim3(512), 128, 0, stream>>>(
        qh, kh, vt, label, dist, contact,
        Wd1, bd1, Wd2, bd2, Wc1, bc1, Wc2, bc2, aout);

    oproj_kernel<<<dim3(256), 256, 0, stream>>>(aout, wt + 3 * HD * HD, bo, (float*)d_out);
}

// Round 9
// 221.223 us; speedup vs baseline: 1.1213x; 1.1213x over previous
//
#include <hip/hip_runtime.h>
#include <hip/hip_bf16.h>

#define SN 2048      // sequence length
#define HD 256       // hidden
#define NHEAD 8
#define DK 32
#define BH 16
#define KCH 4        // split-K chunks
#define KTILES 8     // 64-key tiles per chunk (KCH*KTILES*64 == SN)

typedef __bf16 bf16;
typedef __bf16 bf16x8 __attribute__((ext_vector_type(8)));
typedef __bf16 bf16x4 __attribute__((ext_vector_type(4)));
typedef float f32x4 __attribute__((ext_vector_type(4)));
typedef int i32x4 __attribute__((ext_vector_type(4)));

// ---------------------------------------------------------------------------
// Kernel 1: transpose Wq/Wk/Wv/Wo (fp32 -> bf16, [k][n] -> [n][k]).
// 32 blocks: mat = bid>>3, 32-row stripe rc = bid&7.
// ---------------------------------------------------------------------------
__global__ void __launch_bounds__(256) prep_wt_kernel(
    const float* __restrict__ Wq, const float* __restrict__ Wk,
    const float* __restrict__ Wv, const float* __restrict__ Wo,
    bf16* __restrict__ wt)
{
    __shared__ bf16 tile[32][HD + 8];
    int mat = blockIdx.x >> 3, rc = blockIdx.x & 7;
    int t = threadIdx.x;
    const float* W = mat == 0 ? Wq : mat == 1 ? Wk : mat == 2 ? Wv : Wo;
    bf16* Wt = wt + mat * HD * HD;
    int r0 = rc * 32;
    #pragma unroll
    for (int i = 0; i < 32; i++) tile[i][t] = (bf16)W[(r0 + i) * HD + t];
    __syncthreads();
    #pragma unroll
    for (int i = 0; i < 32; i++) Wt[t * HD + r0 + i] = tile[i][t];
}

// ---------------------------------------------------------------------------
// 2048x256 @ 256x256 GEMM (MFMA 16x16x32 bf16), Wt in [n][k] layout.
// AF32: A fp32 converted in-register. MODE 0: out[m][n]; MODE 1: out[n][m].
// OUTF32: fp32 store (final output).                 [validated R6/R7/R8]
// ---------------------------------------------------------------------------
template<bool AF32, int MODE, bool OUTF32>
__device__ __forceinline__ void gemm_body(
    const void* __restrict__ Ap, const bf16* __restrict__ Wt,
    const float* __restrict__ bias, void* __restrict__ outp, int bid)
{
    int wave = threadIdx.x >> 6, lane = threadIdx.x & 63;
    int g = lane >> 4, qi = lane & 15;
    int mblk = bid & 31, nblk = bid >> 5;
    int m0 = mblk * 64 + wave * 16, n0 = nblk * 32;
    f32x4 acc0 = {0.f, 0.f, 0.f, 0.f}, acc1 = {0.f, 0.f, 0.f, 0.f};
    const bf16* W0 = Wt + (n0 + qi) * HD + 8 * g;
    const bf16* W1 = W0 + 16 * HD;
    #pragma unroll
    for (int ks = 0; ks < 8; ks++) {
        bf16x8 a;
        if constexpr (AF32) {
            const float* Ar = (const float*)Ap + (m0 + qi) * HD + 8 * g + ks * 32;
            f32x4 lo = *(const f32x4*)Ar;
            f32x4 hi = *(const f32x4*)(Ar + 4);
            #pragma unroll
            for (int e = 0; e < 4; e++) { a[e] = (bf16)lo[e]; a[4 + e] = (bf16)hi[e]; }
        } else {
            a = *(const bf16x8*)((const bf16*)Ap + (m0 + qi) * HD + 8 * g + ks * 32);
        }
        bf16x8 b0 = *(const bf16x8*)(W0 + ks * 32);
        bf16x8 b1 = *(const bf16x8*)(W1 + ks * 32);
        acc0 = __builtin_amdgcn_mfma_f32_16x16x32_bf16(a, b0, acc0, 0, 0, 0);
        acc1 = __builtin_amdgcn_mfma_f32_16x16x32_bf16(a, b1, acc1, 0, 0, 0);
    }
    float bv0 = bias[n0 + qi], bv1 = bias[n0 + 16 + qi];
    if constexpr (MODE == 0) {
        if constexpr (OUTF32) {
            float* out = (float*)outp;
            #pragma unroll
            for (int r = 0; r < 4; r++) {
                int m = m0 + 4 * g + r;
                out[m * HD + n0 + qi]      = acc0[r] + bv0;
                out[m * HD + n0 + 16 + qi] = acc1[r] + bv1;
            }
        } else {
            bf16* out = (bf16*)outp;
            #pragma unroll
            for (int r = 0; r < 4; r++) {
                int m = m0 + 4 * g + r;
                out[m * HD + n0 + qi]      = (bf16)(acc0[r] + bv0);
                out[m * HD + n0 + 16 + qi] = (bf16)(acc1[r] + bv1);
            }
        }
    } else {
        bf16* out = (bf16*)outp;
        bf16x4 v0, v1;
        #pragma unroll
        for (int r = 0; r < 4; r++) { v0[r] = (bf16)(acc0[r] + bv0); v1[r] = (bf16)(acc1[r] + bv1); }
        *(bf16x4*)(out + (n0 + qi) * SN + m0 + 4 * g)      = v0;
        *(bf16x4*)(out + (n0 + 16 + qi) * SN + m0 + 4 * g) = v1;
    }
}

__global__ void __launch_bounds__(256) qkv_kernel(
    const float* __restrict__ q, const float* __restrict__ k, const float* __restrict__ v,
    const bf16* __restrict__ wt,
    const float* __restrict__ bq, const float* __restrict__ bk, const float* __restrict__ bv,
    bf16* __restrict__ qh, bf16* __restrict__ kh, bf16* __restrict__ vt)
{
    int w = blockIdx.y;
    if (w == 0)      gemm_body<true, 0, false>(q, wt,               bq, qh, blockIdx.x);
    else if (w == 1) gemm_body<true, 0, false>(k, wt + HD * HD,     bk, kh, blockIdx.x);
    else             gemm_body<true, 1, false>(v, wt + 2 * HD * HD, bv, vt, blockIdx.x);
}

__global__ void __launch_bounds__(256) oproj_kernel(
    const bf16* __restrict__ A, const bf16* __restrict__ wt3,
    const float* __restrict__ bo, float* __restrict__ out)
{
    gemm_body<false, 0, true>(A, wt3, bo, out, blockIdx.x);
}

// ---------------------------------------------------------------------------
// Kernel 3: MFMA flash attention, split-K x4 (flash-decode).
// bid = h*256 + qb*4 + c : all 8 heads of a (q-strip, chunk) share bid%8
// -> same XCD -> map rows L2-reused 8x.
// Each block: 2 waves x 16 q-rows, keys [c*512, c*512+512).
// Barrier-free P exchange: plds[wave] is WAVE-PRIVATE; intra-wave DS
// ordering is guaranteed via lgkmcnt (compiler-tracked). [R8: the two
// __syncthreads forced vmcnt(0) drains every tile = exposed latency]
// Writes unnormalized partial o + (m, l) per chunk; combine_kernel reduces.
// ---------------------------------------------------------------------------
__global__ void __launch_bounds__(128) attn_kernel(
    const bf16* __restrict__ qh, const bf16* __restrict__ kh,
    const bf16* __restrict__ vt,
    const int* __restrict__ label, const float* __restrict__ dist,
    const float* __restrict__ contact,
    const float* __restrict__ Wd1, const float* __restrict__ bd1,
    const float* __restrict__ Wd2, const float* __restrict__ bd2,
    const float* __restrict__ Wc1, const float* __restrict__ bc1,
    const float* __restrict__ Wc2, const float* __restrict__ bc2,
    float* __restrict__ po, float* __restrict__ pm, float* __restrict__ pl)
{
    int wave = threadIdx.x >> 6, lane = threadIdx.x & 63;
    int g = lane >> 4, qi = lane & 15;
    int h = blockIdx.x >> 8, qb = (blockIdx.x >> 2) & 63, c = blockIdx.x & 3;
    int q0 = qb * 32 + wave * 16;
    int kbase = c * (KTILES * 64);

    float ad = 0.f, bld = 0.f, dd = bd2[0];
    #pragma unroll
    for (int j = 0; j < BH; j++) {
        float w2 = Wd2[j];
        ad  += Wd1[j] * w2;
        bld += Wd1[BH + j] * w2;
        dd  += bd1[j] * w2;
    }
    float ac = 0.f, blc = 0.f, dc = bc2[0];
    #pragma unroll
    for (int j = 0; j < BH; j++) {
        float w2 = Wc2[j];
        ac  += Wc1[j] * w2;
        blc += Wc1[BH + j] * w2;
        dc  += bc1[j] * w2;
    }
    float bl = bld + blc, dl = dd + dc;

    __shared__ bf16 plds[2][16][72];
    bf16 (*P)[72] = plds[wave];

    bf16x8 qf = *(const bf16x8*)(qh + (q0 + qi) * HD + h * DK + 8 * g);
    const bf16* kp  = kh + h * DK + 8 * g + kbase * HD;
    const bf16* v0p = vt + (h * DK + qi) * SN + 8 * g + kbase;
    const bf16* v1p = v0p + 16 * SN;
    const float* dp = dist    + (q0 + qi) * SN + 4 * g + kbase;
    const float* cp = contact + (q0 + qi) * SN + 4 * g + kbase;
    const int*   lp = label   + (q0 + qi) * SN + 4 * g + kbase;

    const float scale = 0.17677669529663687f;  // 32^-0.5
    float m = -1e30f, lsum = 0.f;
    f32x4 o0 = {0.f, 0.f, 0.f, 0.f}, o1 = {0.f, 0.f, 0.f, 0.f};

    for (int kt = 0; kt < KTILES; kt++) {
        int key0 = kt * 64;
        bf16x8 kf0 = *(const bf16x8*)(kp + (key0 +  0 + qi) * HD);
        bf16x8 kf1 = *(const bf16x8*)(kp + (key0 + 16 + qi) * HD);
        bf16x8 kf2 = *(const bf16x8*)(kp + (key0 + 32 + qi) * HD);
        bf16x8 kf3 = *(const bf16x8*)(kp + (key0 + 48 + qi) * HD);
        f32x4 dv0 = *(const f32x4*)(dp + key0 +  0), dv1 = *(const f32x4*)(dp + key0 + 16);
        f32x4 dv2 = *(const f32x4*)(dp + key0 + 32), dv3 = *(const f32x4*)(dp + key0 + 48);
        f32x4 cv0 = *(const f32x4*)(cp + key0 +  0), cv1 = *(const f32x4*)(cp + key0 + 16);
        f32x4 cv2 = *(const f32x4*)(cp + key0 + 32), cv3 = *(const f32x4*)(cp + key0 + 48);
        i32x4 lv0 = *(const i32x4*)(lp + key0 +  0), lv1 = *(const i32x4*)(lp + key0 + 16);
        i32x4 lv2 = *(const i32x4*)(lp + key0 + 32), lv3 = *(const i32x4*)(lp + key0 + 48);
        f32x4 zero = {0.f, 0.f, 0.f, 0.f};
        f32x4 s0 = __builtin_amdgcn_mfma_f32_16x16x32_bf16(kf0, qf, zero, 0, 0, 0);
        f32x4 s1 = __builtin_amdgcn_mfma_f32_16x16x32_bf16(kf1, qf, zero, 0, 0, 0);
        f32x4 s2 = __builtin_amdgcn_mfma_f32_16x16x32_bf16(kf2, qf, zero, 0, 0, 0);
        f32x4 s3 = __builtin_amdgcn_mfma_f32_16x16x32_bf16(kf3, qf, zero, 0, 0, 0);
        float x[16];
        #pragma unroll
        for (int r = 0; r < 4; r++) {
            float b0 = ad * dv0[r] + ac * cv0[r] + bl * (float)lv0[r] + dl;
            float b1 = ad * dv1[r] + ac * cv1[r] + bl * (float)lv1[r] + dl;
            float b2 = ad * dv2[r] + ac * cv2[r] + bl * (float)lv2[r] + dl;
            float b3 = ad * dv3[r] + ac * cv3[r] + bl * (float)lv3[r] + dl;
            x[r]      = s0[r] * scale + b0;
            x[4 + r]  = s1[r] * scale + b1;
            x[8 + r]  = s2[r] * scale + b2;
            x[12 + r] = s3[r] * scale + b3;
        }
        // tree max (depth 4) instead of 15-deep chain
        float t0 = fmaxf(x[0], x[1]),  t1 = fmaxf(x[2], x[3]);
        float t2 = fmaxf(x[4], x[5]),  t3 = fmaxf(x[6], x[7]);
        float t4 = fmaxf(x[8], x[9]),  t5 = fmaxf(x[10], x[11]);
        float t6 = fmaxf(x[12], x[13]), t7 = fmaxf(x[14], x[15]);
        float tm = fmaxf(fmaxf(fmaxf(t0, t1), fmaxf(t2, t3)),
                         fmaxf(fmaxf(t4, t5), fmaxf(t6, t7)));
        tm = fmaxf(tm, __shfl_xor(tm, 16));
        tm = fmaxf(tm, __shfl_xor(tm, 32));
        float mnew = fmaxf(m, tm);
        float f = __expf(m - mnew);
        float ps = 0.f;
        #pragma unroll
        for (int i = 0; i < 16; i++) { x[i] = __expf(x[i] - mnew); ps += x[i]; }
        ps += __shfl_xor(ps, 16);
        ps += __shfl_xor(ps, 32);
        lsum = lsum * f + ps;
        m = mnew;
        #pragma unroll
        for (int r = 0; r < 4; r++) { o0[r] *= f; o1[r] *= f; }
        // P exchange through wave-private LDS (no block barrier needed)
        #pragma unroll
        for (int s = 0; s < 4; s++) {
            bf16x4 pv;
            #pragma unroll
            for (int r = 0; r < 4; r++) pv[r] = (bf16)x[s * 4 + r];
            *(bf16x4*)(&P[qi][16 * s + 4 * g]) = pv;
        }
        asm volatile("" ::: "memory");  // keep write -> read order at compile time
        bf16x4 pa0 = *(const bf16x4*)(&P[qi][8 * g]);
        bf16x4 pa1 = *(const bf16x4*)(&P[qi][8 * g + 4]);
        bf16x4 pa2 = *(const bf16x4*)(&P[qi][32 + 8 * g]);
        bf16x4 pa3 = *(const bf16x4*)(&P[qi][32 + 8 * g + 4]);
        asm volatile("" ::: "memory");  // keep read -> next write order (WAR)
        bf16x8 pb0 = __builtin_shufflevector(pa0, pa1, 0, 1, 2, 3, 4, 5, 6, 7);
        bf16x8 pb1 = __builtin_shufflevector(pa2, pa3, 0, 1, 2, 3, 4, 5, 6, 7);
        bf16x8 va00 = *(const bf16x8*)(v0p + key0);
        bf16x8 va01 = *(const bf16x8*)(v0p + key0 + 32);
        bf16x8 va10 = *(const bf16x8*)(v1p + key0);
        bf16x8 va11 = *(const bf16x8*)(v1p + key0 + 32);
        o0 = __builtin_amdgcn_mfma_f32_16x16x32_bf16(va00, pb0, o0, 0, 0, 0);
        o0 = __builtin_amdgcn_mfma_f32_16x16x32_bf16(va01, pb1, o0, 0, 0, 0);
        o1 = __builtin_amdgcn_mfma_f32_16x16x32_bf16(va10, pb0, o1, 0, 0, 0);
        o1 = __builtin_amdgcn_mfma_f32_16x16x32_bf16(va11, pb1, o1, 0, 0, 0);
    }
    // partial write: o unnormalized (scaled to local max), plus (m, lsum)
    int hq = h * SN + q0 + qi;
    *(f32x4*)(po + (hq * KCH + c) * DK + 4 * g)      = o0;
    *(f32x4*)(po + (hq * KCH + c) * DK + 16 + 4 * g) = o1;
    if (g == 0) { pm[hq * KCH + c] = m; pl[hq * KCH + c] = lsum; }
}

// ---------------------------------------------------------------------------
// Kernel 4: split-K combine. One thread per (h, q, d).
// ---------------------------------------------------------------------------
__global__ void __launch_bounds__(256) combine_kernel(
    const float* __restrict__ po, const float* __restrict__ pm,
    const float* __restrict__ pl, bf16* __restrict__ aout)
{
    int idx = blockIdx.x * 256 + threadIdx.x;
    int d = idx & (DK - 1), hq = idx >> 5;
    int h = hq >> 11, qr = hq & (SN - 1);
    f32x4 mv = *(const f32x4*)(pm + hq * KCH);
    f32x4 lv = *(const f32x4*)(pl + hq * KCH);
    float M = fmaxf(fmaxf(mv[0], mv[1]), fmaxf(mv[2], mv[3]));
    float w0 = __expf(mv[0] - M), w1 = __expf(mv[1] - M);
    float w2 = __expf(mv[2] - M), w3 = __expf(mv[3] - M);
    float L = w0 * lv[0] + w1 * lv[1] + w2 * lv[2] + w3 * lv[3];
    const float* p = po + hq * KCH * DK + d;
    float o = w0 * p[0] + w1 * p[DK] + w2 * p[2 * DK] + w3 * p[3 * DK];
    aout[qr * HD + h * DK + d] = (bf16)(o / L);
}

// ---------------------------------------------------------------------------
extern "C" void kernel_launch(void* const* d_in, const int* in_sizes, int n_in,
                              void* d_out, int out_size, void* d_ws, size_t ws_size,
                              hipStream_t stream)
{
    static const int expect[22] = {
        SN * SN, SN * SN, SN * SN,
        SN * HD, SN * HD, SN * HD,
        HD * HD, HD, HD * HD, HD,
        HD * HD, HD, HD * HD, HD,
        2 * BH, BH, BH, 1,
        2 * BH, BH, BH, 1
    };
    if (n_in != 22) return;
    for (int i = 0; i < 22; i++) if (in_sizes[i] != expect[i]) return;

    const int*   label   = (const int*)  d_in[0];
    const float* dist    = (const float*)d_in[1];
    const float* contact = (const float*)d_in[2];
    const float* q  = (const float*)d_in[3];
    const float* k  = (const float*)d_in[4];
    const float* v  = (const float*)d_in[5];
    const float* Wq = (const float*)d_in[6];  const float* bq = (const float*)d_in[7];
    const float* Wk = (const float*)d_in[8];  const float* bk = (const float*)d_in[9];
    const float* Wv = (const float*)d_in[10]; const float* bv = (const float*)d_in[11];
    const float* Wo = (const float*)d_in[12]; const float* bo = (const float*)d_in[13];
    const float* Wd1 = (const float*)d_in[14]; const float* bd1 = (const float*)d_in[15];
    const float* Wd2 = (const float*)d_in[16]; const float* bd2 = (const float*)d_in[17];
    const float* Wc1 = (const float*)d_in[18]; const float* bc1 = (const float*)d_in[19];
    const float* Wc2 = (const float*)d_in[20]; const float* bc2 = (const float*)d_in[21];

    // ws: 13.5 MB
    char* ws = (char*)d_ws;
    bf16*  qh   = (bf16*)(ws);                  // 1 MB projected Q [N][256]
    bf16*  kh   = (bf16*)(ws + (1u << 20));     // 1 MB projected K [N][256]
    bf16*  vt   = (bf16*)(ws + (2u << 20));     // 1 MB projected V transposed [256][N]
    bf16*  aout = (bf16*)(ws + (3u << 20));     // 1 MB attention output [N][256]
    bf16*  wt   = (bf16*)(ws + (4u << 20));     // 512 KB transposed weights x4
    float* po   = (float*)(ws + (5u << 20));    // 8 MB partial O [8*2048][4][32]
    float* pm   = (float*)(ws + (13u << 20));   // 256 KB partial max
    float* pl   = (float*)(ws + (13u << 20) + (256u << 10)); // 256 KB partial lsum

    prep_wt_kernel<<<dim3(32), 256, 0, stream>>>(Wq, Wk, Wv, Wo, wt);

    qkv_kernel<<<dim3(256, 3), 256, 0, stream>>>(q, k, v, wt, bq, bk, bv, qh, kh, vt);

    attn_kernel<<<dim3(NHEAD * 64 * KCH), 128, 0, stream>>>(
        qh, kh, vt, label, dist, contact,
        Wd1, bd1, Wd2, bd2, Wc1, bc1, Wc2, bc2, po, pm, pl);

    combine_kernel<<<dim3(NHEAD * SN * DK / 256), 256, 0, stream>>>(po, pm, pl, aout);

    oproj_kernel<<<dim3(256), 256, 0, stream>>>(aout, wt + 3 * HD * HD, bo, (float*)d_out);
}

// Round 10
// 217.445 us; speedup vs baseline: 1.1408x; 1.0174x over previous
//
#include <hip/hip_runtime.h>
#include <hip/hip_bf16.h>

#define SN 2048      // sequence length
#define HD 256       // hidden
#define NHEAD 8
#define DK 32
#define BH 16
#define KCH 4        // split-K chunks
#define KTILES 8     // 64-key tiles per chunk (KCH*KTILES*64 == SN)

typedef __bf16 bf16;
typedef __bf16 bf16x8 __attribute__((ext_vector_type(8)));
typedef __bf16 bf16x4 __attribute__((ext_vector_type(4)));
typedef float f32x4 __attribute__((ext_vector_type(4)));
typedef int i32x4 __attribute__((ext_vector_type(4)));

// ---------------------------------------------------------------------------
// Kernel 1: transpose Wq/Wk/Wv/Wo (fp32 -> bf16, [k][n] -> [n][k]).
// 32 blocks: mat = bid>>3, 32-row stripe rc = bid&7.
// ---------------------------------------------------------------------------
__global__ void __launch_bounds__(256) prep_wt_kernel(
    const float* __restrict__ Wq, const float* __restrict__ Wk,
    const float* __restrict__ Wv, const float* __restrict__ Wo,
    bf16* __restrict__ wt)
{
    __shared__ bf16 tile[32][HD + 8];
    int mat = blockIdx.x >> 3, rc = blockIdx.x & 7;
    int t = threadIdx.x;
    const float* W = mat == 0 ? Wq : mat == 1 ? Wk : mat == 2 ? Wv : Wo;
    bf16* Wt = wt + mat * HD * HD;
    int r0 = rc * 32;
    #pragma unroll
    for (int i = 0; i < 32; i++) tile[i][t] = (bf16)W[(r0 + i) * HD + t];
    __syncthreads();
    #pragma unroll
    for (int i = 0; i < 32; i++) Wt[t * HD + r0 + i] = tile[i][t];
}

// ---------------------------------------------------------------------------
// 2048x256 @ 256x256 GEMM (MFMA 16x16x32 bf16), Wt [n][k]. 2-deep register
// prefetch rotation (load ks+1 while MFMA ks) — R9 was latency-bound.
// AF32: A fp32 converted in-register. MODE 0: out[m][n]; MODE 1: out[n][m].
// OUTF32: fp32 store (final output).
// ---------------------------------------------------------------------------
template<bool AF32, int MODE, bool OUTF32>
__device__ __forceinline__ void gemm_body(
    const void* __restrict__ Ap, const bf16* __restrict__ Wt,
    const float* __restrict__ bias, void* __restrict__ outp, int bid)
{
    int wave = threadIdx.x >> 6, lane = threadIdx.x & 63;
    int g = lane >> 4, qi = lane & 15;
    int mblk = bid & 31, nblk = bid >> 5;
    int m0 = mblk * 64 + wave * 16, n0 = nblk * 32;
    f32x4 acc0 = {0.f, 0.f, 0.f, 0.f}, acc1 = {0.f, 0.f, 0.f, 0.f};
    const bf16* W0 = Wt + (n0 + qi) * HD + 8 * g;
    const bf16* W1 = W0 + 16 * HD;

    auto loadA = [&](int ks) -> bf16x8 {
        if constexpr (AF32) {
            const float* Ar = (const float*)Ap + (m0 + qi) * HD + 8 * g + ks * 32;
            f32x4 lo = *(const f32x4*)Ar;
            f32x4 hi = *(const f32x4*)(Ar + 4);
            bf16x8 a;
            #pragma unroll
            for (int e = 0; e < 4; e++) { a[e] = (bf16)lo[e]; a[4 + e] = (bf16)hi[e]; }
            return a;
        } else {
            return *(const bf16x8*)((const bf16*)Ap + (m0 + qi) * HD + 8 * g + ks * 32);
        }
    };

    bf16x8 a_c  = loadA(0);
    bf16x8 b0_c = *(const bf16x8*)(W0);
    bf16x8 b1_c = *(const bf16x8*)(W1);
    #pragma unroll
    for (int ks = 0; ks < 8; ks++) {
        bf16x8 a_n, b0_n, b1_n;
        if (ks < 7) {
            a_n  = loadA(ks + 1);
            b0_n = *(const bf16x8*)(W0 + (ks + 1) * 32);
            b1_n = *(const bf16x8*)(W1 + (ks + 1) * 32);
        }
        acc0 = __builtin_amdgcn_mfma_f32_16x16x32_bf16(a_c, b0_c, acc0, 0, 0, 0);
        acc1 = __builtin_amdgcn_mfma_f32_16x16x32_bf16(a_c, b1_c, acc1, 0, 0, 0);
        if (ks < 7) { a_c = a_n; b0_c = b0_n; b1_c = b1_n; }
    }
    float bv0 = bias[n0 + qi], bv1 = bias[n0 + 16 + qi];
    if constexpr (MODE == 0) {
        if constexpr (OUTF32) {
            float* out = (float*)outp;
            #pragma unroll
            for (int r = 0; r < 4; r++) {
                int m = m0 + 4 * g + r;
                out[m * HD + n0 + qi]      = acc0[r] + bv0;
                out[m * HD + n0 + 16 + qi] = acc1[r] + bv1;
            }
        } else {
            bf16* out = (bf16*)outp;
            #pragma unroll
            for (int r = 0; r < 4; r++) {
                int m = m0 + 4 * g + r;
                out[m * HD + n0 + qi]      = (bf16)(acc0[r] + bv0);
                out[m * HD + n0 + 16 + qi] = (bf16)(acc1[r] + bv1);
            }
        }
    } else {
        bf16* out = (bf16*)outp;
        bf16x4 v0, v1;
        #pragma unroll
        for (int r = 0; r < 4; r++) { v0[r] = (bf16)(acc0[r] + bv0); v1[r] = (bf16)(acc1[r] + bv1); }
        *(bf16x4*)(out + (n0 + qi) * SN + m0 + 4 * g)      = v0;
        *(bf16x4*)(out + (n0 + 16 + qi) * SN + m0 + 4 * g) = v1;
    }
}

__global__ void __launch_bounds__(256) qkv_kernel(
    const float* __restrict__ q, const float* __restrict__ k, const float* __restrict__ v,
    const bf16* __restrict__ wt,
    const float* __restrict__ bq, const float* __restrict__ bk, const float* __restrict__ bv,
    bf16* __restrict__ qh, bf16* __restrict__ kh, bf16* __restrict__ vt)
{
    int w = blockIdx.y;
    if (w == 0)      gemm_body<true, 0, false>(q, wt,               bq, qh, blockIdx.x);
    else if (w == 1) gemm_body<true, 0, false>(k, wt + HD * HD,     bk, kh, blockIdx.x);
    else             gemm_body<true, 1, false>(v, wt + 2 * HD * HD, bv, vt, blockIdx.x);
}

__global__ void __launch_bounds__(256) oproj_kernel(
    const bf16* __restrict__ A, const bf16* __restrict__ wt3,
    const float* __restrict__ bo, float* __restrict__ out)
{
    gemm_body<false, 0, true>(A, wt3, bo, out, blockIdx.x);
}

// ---------------------------------------------------------------------------
// Kernel 3: MFMA flash attention, split-K x4, SOFTWARE-PIPELINED:
// tile t+1's K-fragments + bias-map vectors are issued at the top of
// iteration t (R9 counters: 88 µs with VALU 18% / HBM 10% / Mfma 1.9% =
// pure exposed latency; the serial chain was the whole cost).
// V loads issue before the softmax chain (hidden under it).
// Barrier-free P exchange via wave-private LDS (compile-time ordering only).
// ---------------------------------------------------------------------------
__global__ void __launch_bounds__(128) attn_kernel(
    const bf16* __restrict__ qh, const bf16* __restrict__ kh,
    const bf16* __restrict__ vt,
    const int* __restrict__ label, const float* __restrict__ dist,
    const float* __restrict__ contact,
    const float* __restrict__ Wd1, const float* __restrict__ bd1,
    const float* __restrict__ Wd2, const float* __restrict__ bd2,
    const float* __restrict__ Wc1, const float* __restrict__ bc1,
    const float* __restrict__ Wc2, const float* __restrict__ bc2,
    float* __restrict__ po, float* __restrict__ pm, float* __restrict__ pl)
{
    int wave = threadIdx.x >> 6, lane = threadIdx.x & 63;
    int g = lane >> 4, qi = lane & 15;
    int h = blockIdx.x >> 8, qb = (blockIdx.x >> 2) & 63, c = blockIdx.x & 3;
    int q0 = qb * 32 + wave * 16;
    int kbase = c * (KTILES * 64);

    __shared__ bf16 plds[2][16][72];
    bf16 (*P)[72] = plds[wave];

    bf16x8 qf = *(const bf16x8*)(qh + (q0 + qi) * HD + h * DK + 8 * g);
    const bf16* kp  = kh + h * DK + 8 * g + kbase * HD;
    const bf16* v0p = vt + (h * DK + qi) * SN + 8 * g + kbase;
    const bf16* v1p = v0p + 16 * SN;
    const float* dp = dist    + (q0 + qi) * SN + 4 * g + kbase;
    const float* cp = contact + (q0 + qi) * SN + 4 * g + kbase;
    const int*   lp = label   + (q0 + qi) * SN + 4 * g + kbase;

    auto load_k = [&](int key0, bf16x8* kf) {
        kf[0] = *(const bf16x8*)(kp + (key0 +  0 + qi) * HD);
        kf[1] = *(const bf16x8*)(kp + (key0 + 16 + qi) * HD);
        kf[2] = *(const bf16x8*)(kp + (key0 + 32 + qi) * HD);
        kf[3] = *(const bf16x8*)(kp + (key0 + 48 + qi) * HD);
    };
    auto load_b = [&](int key0, f32x4* dv, f32x4* cv, i32x4* lv) {
        #pragma unroll
        for (int s = 0; s < 4; s++) {
            dv[s] = *(const f32x4*)(dp + key0 + 16 * s);
            cv[s] = *(const f32x4*)(cp + key0 + 16 * s);
            lv[s] = *(const i32x4*)(lp + key0 + 16 * s);
        }
    };

    // issue tile-0 loads BEFORE the (scalar) MLP fold: latency overlaps it
    bf16x8 kf[4]; f32x4 dv[4], cv[4]; i32x4 lv[4];
    load_k(0, kf);
    load_b(0, dv, cv, lv);

    // fold the two affine pair-MLPs into 4 scalars (wave-uniform, fp32)
    float ad = 0.f, bld = 0.f, dd = bd2[0];
    #pragma unroll
    for (int j = 0; j < BH; j++) {
        float w2 = Wd2[j];
        ad  += Wd1[j] * w2;
        bld += Wd1[BH + j] * w2;
        dd  += bd1[j] * w2;
    }
    float ac = 0.f, blc = 0.f, dc = bc2[0];
    #pragma unroll
    for (int j = 0; j < BH; j++) {
        float w2 = Wc2[j];
        ac  += Wc1[j] * w2;
        blc += Wc1[BH + j] * w2;
        dc  += bc1[j] * w2;
    }
    float bl = bld + blc, dl = dd + dc;

    const float scale = 0.17677669529663687f;  // 32^-0.5
    float m = -1e30f, lsum = 0.f;
    f32x4 o0 = {0.f, 0.f, 0.f, 0.f}, o1 = {0.f, 0.f, 0.f, 0.f};

    #pragma unroll
    for (int kt = 0; kt < KTILES; kt++) {
        int key0 = kt * 64;
        // prefetch tile kt+1 (compile-time guarded; issues ~1 tile early)
        bf16x8 kfn[4]; f32x4 dvn[4], cvn[4]; i32x4 lvn[4];
        if (kt + 1 < KTILES) {
            load_k(key0 + 64, kfn);
            load_b(key0 + 64, dvn, cvn, lvn);
        }
        // V loads for the CURRENT tile: issue now, consumed after softmax
        bf16x8 va00 = *(const bf16x8*)(v0p + key0);
        bf16x8 va01 = *(const bf16x8*)(v0p + key0 + 32);
        bf16x8 va10 = *(const bf16x8*)(v1p + key0);
        bf16x8 va11 = *(const bf16x8*)(v1p + key0 + 32);

        f32x4 zero = {0.f, 0.f, 0.f, 0.f};
        f32x4 s0 = __builtin_amdgcn_mfma_f32_16x16x32_bf16(kf[0], qf, zero, 0, 0, 0);
        f32x4 s1 = __builtin_amdgcn_mfma_f32_16x16x32_bf16(kf[1], qf, zero, 0, 0, 0);
        f32x4 s2 = __builtin_amdgcn_mfma_f32_16x16x32_bf16(kf[2], qf, zero, 0, 0, 0);
        f32x4 s3 = __builtin_amdgcn_mfma_f32_16x16x32_bf16(kf[3], qf, zero, 0, 0, 0);
        float x[16];
        #pragma unroll
        for (int r = 0; r < 4; r++) {
            float b0 = ad * dv[0][r] + ac * cv[0][r] + bl * (float)lv[0][r] + dl;
            float b1 = ad * dv[1][r] + ac * cv[1][r] + bl * (float)lv[1][r] + dl;
            float b2 = ad * dv[2][r] + ac * cv[2][r] + bl * (float)lv[2][r] + dl;
            float b3 = ad * dv[3][r] + ac * cv[3][r] + bl * (float)lv[3][r] + dl;
            x[r]      = s0[r] * scale + b0;
            x[4 + r]  = s1[r] * scale + b1;
            x[8 + r]  = s2[r] * scale + b2;
            x[12 + r] = s3[r] * scale + b3;
        }
        float t0 = fmaxf(x[0], x[1]),   t1 = fmaxf(x[2], x[3]);
        float t2 = fmaxf(x[4], x[5]),   t3 = fmaxf(x[6], x[7]);
        float t4 = fmaxf(x[8], x[9]),   t5 = fmaxf(x[10], x[11]);
        float t6 = fmaxf(x[12], x[13]), t7 = fmaxf(x[14], x[15]);
        float tm = fmaxf(fmaxf(fmaxf(t0, t1), fmaxf(t2, t3)),
                         fmaxf(fmaxf(t4, t5), fmaxf(t6, t7)));
        tm = fmaxf(tm, __shfl_xor(tm, 16));
        tm = fmaxf(tm, __shfl_xor(tm, 32));
        float mnew = fmaxf(m, tm);
        float f = __expf(m - mnew);
        float ps = 0.f;
        #pragma unroll
        for (int i = 0; i < 16; i++) { x[i] = __expf(x[i] - mnew); ps += x[i]; }
        ps += __shfl_xor(ps, 16);
        ps += __shfl_xor(ps, 32);
        lsum = lsum * f + ps;
        m = mnew;
        #pragma unroll
        for (int r = 0; r < 4; r++) { o0[r] *= f; o1[r] *= f; }
        // P exchange through wave-private LDS (no block barrier needed)
        #pragma unroll
        for (int s = 0; s < 4; s++) {
            bf16x4 pv;
            #pragma unroll
            for (int r = 0; r < 4; r++) pv[r] = (bf16)x[s * 4 + r];
            *(bf16x4*)(&P[qi][16 * s + 4 * g]) = pv;
        }
        asm volatile("" ::: "memory");  // compile-time: write before read
        bf16x4 pa0 = *(const bf16x4*)(&P[qi][8 * g]);
        bf16x4 pa1 = *(const bf16x4*)(&P[qi][8 * g + 4]);
        bf16x4 pa2 = *(const bf16x4*)(&P[qi][32 + 8 * g]);
        bf16x4 pa3 = *(const bf16x4*)(&P[qi][32 + 8 * g + 4]);
        asm volatile("" ::: "memory");  // compile-time: read before next write
        bf16x8 pb0 = __builtin_shufflevector(pa0, pa1, 0, 1, 2, 3, 4, 5, 6, 7);
        bf16x8 pb1 = __builtin_shufflevector(pa2, pa3, 0, 1, 2, 3, 4, 5, 6, 7);
        o0 = __builtin_amdgcn_mfma_f32_16x16x32_bf16(va00, pb0, o0, 0, 0, 0);
        o0 = __builtin_amdgcn_mfma_f32_16x16x32_bf16(va01, pb1, o0, 0, 0, 0);
        o1 = __builtin_amdgcn_mfma_f32_16x16x32_bf16(va10, pb0, o1, 0, 0, 0);
        o1 = __builtin_amdgcn_mfma_f32_16x16x32_bf16(va11, pb1, o1, 0, 0, 0);
        if (kt + 1 < KTILES) {
            #pragma unroll
            for (int s = 0; s < 4; s++) { kf[s] = kfn[s]; dv[s] = dvn[s]; cv[s] = cvn[s]; lv[s] = lvn[s]; }
        }
    }
    int hq = h * SN + q0 + qi;
    *(f32x4*)(po + (hq * KCH + c) * DK + 4 * g)      = o0;
    *(f32x4*)(po + (hq * KCH + c) * DK + 16 + 4 * g) = o1;
    if (g == 0) { pm[hq * KCH + c] = m; pl[hq * KCH + c] = lsum; }
}

// ---------------------------------------------------------------------------
// Kernel 4: split-K combine. One thread per (h, q, d).
// ---------------------------------------------------------------------------
__global__ void __launch_bounds__(256) combine_kernel(
    const float* __restrict__ po, const float* __restrict__ pm,
    const float* __restrict__ pl, bf16* __restrict__ aout)
{
    int idx = blockIdx.x * 256 + threadIdx.x;
    int d = idx & (DK - 1), hq = idx >> 5;
    int h = hq >> 11, qr = hq & (SN - 1);
    f32x4 mv = *(const f32x4*)(pm + hq * KCH);
    f32x4 lv = *(const f32x4*)(pl + hq * KCH);
    float M = fmaxf(fmaxf(mv[0], mv[1]), fmaxf(mv[2], mv[3]));
    float w0 = __expf(mv[0] - M), w1 = __expf(mv[1] - M);
    float w2 = __expf(mv[2] - M), w3 = __expf(mv[3] - M);
    float L = w0 * lv[0] + w1 * lv[1] + w2 * lv[2] + w3 * lv[3];
    const float* p = po + hq * KCH * DK + d;
    float o = w0 * p[0] + w1 * p[DK] + w2 * p[2 * DK] + w3 * p[3 * DK];
    aout[qr * HD + h * DK + d] = (bf16)(o / L);
}

// ---------------------------------------------------------------------------
extern "C" void kernel_launch(void* const* d_in, const int* in_sizes, int n_in,
                              void* d_out, int out_size, void* d_ws, size_t ws_size,
                              hipStream_t stream)
{
    static const int expect[22] = {
        SN * SN, SN * SN, SN * SN,
        SN * HD, SN * HD, SN * HD,
        HD * HD, HD, HD * HD, HD,
        HD * HD, HD, HD * HD, HD,
        2 * BH, BH, BH, 1,
        2 * BH, BH, BH, 1
    };
    if (n_in != 22) return;
    for (int i = 0; i < 22; i++) if (in_sizes[i] != expect[i]) return;

    const int*   label   = (const int*)  d_in[0];
    const float* dist    = (const float*)d_in[1];
    const float* contact = (const float*)d_in[2];
    const float* q  = (const float*)d_in[3];
    const float* k  = (const float*)d_in[4];
    const float* v  = (const float*)d_in[5];
    const float* Wq = (const float*)d_in[6];  const float* bq = (const float*)d_in[7];
    const float* Wk = (const float*)d_in[8];  const float* bk = (const float*)d_in[9];
    const float* Wv = (const float*)d_in[10]; const float* bv = (const float*)d_in[11];
    const float* Wo = (const float*)d_in[12]; const float* bo = (const float*)d_in[13];
    const float* Wd1 = (const float*)d_in[14]; const float* bd1 = (const float*)d_in[15];
    const float* Wd2 = (const float*)d_in[16]; const float* bd2 = (const float*)d_in[17];
    const float* Wc1 = (const float*)d_in[18]; const float* bc1 = (const float*)d_in[19];
    const float* Wc2 = (const float*)d_in[20]; const float* bc2 = (const float*)d_in[21];

    // ws: 13.5 MB
    char* ws = (char*)d_ws;
    bf16*  qh   = (bf16*)(ws);                  // 1 MB projected Q [N][256]
    bf16*  kh   = (bf16*)(ws + (1u << 20));     // 1 MB projected K [N][256]
    bf16*  vt   = (bf16*)(ws + (2u << 20));     // 1 MB projected V transposed [256][N]
    bf16*  aout = (bf16*)(ws + (3u << 20));     // 1 MB attention output [N][256]
    bf16*  wt   = (bf16*)(ws + (4u << 20));     // 512 KB transposed weights x4
    float* po   = (float*)(ws + (5u << 20));    // 8 MB partial O [8*2048][4][32]
    float* pm   = (float*)(ws + (13u << 20));   // 256 KB partial max
    float* pl   = (float*)(ws + (13u << 20) + (256u << 10)); // 256 KB partial lsum

    prep_wt_kernel<<<dim3(32), 256, 0, stream>>>(Wq, Wk, Wv, Wo, wt);

    qkv_kernel<<<dim3(256, 3), 256, 0, stream>>>(q, k, v, wt, bq, bk, bv, qh, kh, vt);

    attn_kernel<<<dim3(NHEAD * 64 * KCH), 128, 0, stream>>>(
        qh, kh, vt, label, dist, contact,
        Wd1, bd1, Wd2, bd2, Wc1, bc1, Wc2, bc2, po, pm, pl);

    combine_kernel<<<dim3(NHEAD * SN * DK / 256), 256, 0, stream>>>(po, pm, pl, aout);

    oproj_kernel<<<dim3(256), 256, 0, stream>>>(aout, wt + 3 * HD * HD, bo, (float*)d_out);
}